// Round 1
// 460.934 us; speedup vs baseline: 1.3200x; 1.3200x over previous
//
#include <hip/hip_runtime.h>

// SimpleRNN fused kernel for MI355X (gfx950).
// B=256, T=512, I=64, H=256, O=1, fp32.
//
// Decomposition: 256 blocks (one per batch row) x 512 threads.
// Lane (j = tid>>1, half = tid&1) owns W_hh[j][half*128 .. +127] (128 VGPRs)
// and W_ih[j][half*32 .. +31] (32 VGPRs). h is broadcast via LDS
// (double-buffered, one barrier per step). No cross-block communication.
//
// R1: de-bank the half-split LDS reads. A wave's 64 lanes read exactly two
// distinct addresses (half=0 at c*16 B, half=1 at 512 + c*16 B). 512 B is a
// multiple of 32 banks, so both addresses hit the SAME bank group -> 2-row
// conflict on every ds_read_b128 (measured 1.34e8 conflict cycles ~= 1/3 of
// runtime). Padding the half boundary by +16 B (4 floats) moves half=1 onto
// banks 4c+4..4c+7, disjoint from half=0's 4c..4c+3 -> conflict-free
// broadcast reads. Same fix for xbuf (pad +4 floats at the 32-float split).

#define RNN_B 256
#define RNN_T 512
#define RNN_I 64
#define RNN_H 256

// padded layouts: h[0..127] at [0..127], h[128..255] at [132..259]
//                 x[0..31]  at [0..31],  x[32..63]   at [36..67]
#define HSTRIDE 132   // float offset of half-1 h data
#define XSTRIDE 36    // float offset of half-1 x data

__global__ __launch_bounds__(512, 2)
void rnn_fused_kernel(const float* __restrict__ x,     // [B,T,I]
                      const float* __restrict__ W_ih,  // [H,I]
                      const float* __restrict__ W_hh,  // [H,H]
                      const float* __restrict__ b_ih,  // [H]
                      const float* __restrict__ b_hh,  // [H]
                      const float* __restrict__ fc_W,  // [O,H], O=1
                      const float* __restrict__ fc_b,  // [O]
                      float* __restrict__ out)         // [B,O]
{
    const int b    = blockIdx.x;
    const int tid  = threadIdx.x;   // 0..511
    const int j    = tid >> 1;      // output hidden index 0..255
    const int half = tid & 1;       // which half of the k-reduction

    __shared__ float hbuf[2][260];     // double-buffered hidden state (padded)
    __shared__ float xbuf[2][68];      // double-buffered x_t (padded)
    __shared__ float red[8];           // final block reduction

    // padded write index for h[j]
    const int jofs = j + ((j >> 7) << 2);          // j<128 -> j, else j+4
    // padded float4 write index for x staging (valid for tid<16)
    const int xofs = (tid << 2) + (((tid >> 3) & 1) << 2);

    // ---- register-resident weights ----
    float4 wh[32];  // W_hh[j][half*128 + 4c + {0..3}]
    float4 wi[8];   // W_ih[j][half*32  + 4c + {0..3}]
    {
        const float4* src = reinterpret_cast<const float4*>(W_hh + j * RNN_H + half * 128);
        #pragma unroll
        for (int c = 0; c < 32; ++c) wh[c] = src[c];
        const float4* s2 = reinterpret_cast<const float4*>(W_ih + j * RNN_I + half * 32);
        #pragma unroll
        for (int c = 0; c < 8; ++c) wi[c] = s2[c];
    }
    const float bias2 = b_ih[j] + b_hh[j];
    const float fcw   = fc_W[j];

    // ---- prologue: h0 = 0, stage x[b,0,:] ----
    if (half == 0) hbuf[0][jofs] = 0.0f;
    if (tid < 16) {
        const float4* xs = reinterpret_cast<const float4*>(x + (size_t)b * RNN_T * RNN_I);
        *reinterpret_cast<float4*>(&xbuf[0][xofs]) = xs[tid];
    }
    __syncthreads();

    float hj = 0.0f;  // this lane's h_new[j] (valid every step; identical in lane pairs)

    const float* hbase0 = &hbuf[0][half * HSTRIDE];
    const float* hbase1 = &hbuf[1][half * HSTRIDE];
    const float* xbase0 = &xbuf[0][half * XSTRIDE];
    const float* xbase1 = &xbuf[1][half * XSTRIDE];

    for (int t = 0; t < RNN_T; ++t) {
        const int cur = t & 1;
        const int nxt = cur ^ 1;

        // prefetch x[b, t+1, :] (wave 0, lanes 0..15)
        float4 xpre;
        const bool doPre = (tid < 16) && (t + 1 < RNN_T);
        if (doPre) {
            xpre = reinterpret_cast<const float4*>(
                       x + ((size_t)b * RNN_T + (t + 1)) * RNN_I)[tid];
        }

        // partial_j = sum over this lane's k-half of h[k]*W_hh[j,k] + x[k]*W_ih[j,k]
        float a0 = 0.f, a1 = 0.f, a2 = 0.f, a3 = 0.f;
        const float4* hs = reinterpret_cast<const float4*>(cur ? hbase1 : hbase0);
        #pragma unroll
        for (int c = 0; c < 32; ++c) {
            const float4 h4 = hs[c];   // broadcast read; halves on disjoint banks
            a0 = fmaf(h4.x, wh[c].x, a0);
            a1 = fmaf(h4.y, wh[c].y, a1);
            a2 = fmaf(h4.z, wh[c].z, a2);
            a3 = fmaf(h4.w, wh[c].w, a3);
        }
        const float4* xs4 = reinterpret_cast<const float4*>(cur ? xbase1 : xbase0);
        #pragma unroll
        for (int c = 0; c < 8; ++c) {
            const float4 x4 = xs4[c];
            a0 = fmaf(x4.x, wi[c].x, a0);
            a1 = fmaf(x4.y, wi[c].y, a1);
            a2 = fmaf(x4.z, wi[c].z, a2);
            a3 = fmaf(x4.w, wi[c].w, a3);
        }
        float partial = (a0 + a1) + (a2 + a3);
        partial += __shfl_xor(partial, 1, 64);   // add partner half's partial

        // h_new[j] = tanh(partial + bias2); computed redundantly in both lanes of pair
        const float z  = partial + bias2;
        const float zc = fminf(fmaxf(z, -10.f), 10.f);
        const float e  = exp2f(zc * 2.8853900817779268f);     // e^(2z)
        const float hn = (e - 1.f) * __builtin_amdgcn_rcpf(e + 1.f);
        hj = hn;

        if (half == 0) hbuf[nxt][jofs] = hn;
        if (doPre) *reinterpret_cast<float4*>(&xbuf[nxt][xofs]) = xpre;
        __syncthreads();
    }

    // ---- epilogue: out[b] = sum_j h_T[j]*fc_W[j] + fc_b ----
    float term = (half == 0) ? hj * fcw : 0.0f;
    #pragma unroll
    for (int s = 1; s < 64; s <<= 1) term += __shfl_xor(term, s, 64);
    const int wid = tid >> 6;
    if ((tid & 63) == 0) red[wid] = term;
    __syncthreads();
    if (tid == 0) {
        float s = 0.f;
        #pragma unroll
        for (int w = 0; w < 8; ++w) s += red[w];
        out[b] = s + fc_b[0];
    }
}

extern "C" void kernel_launch(void* const* d_in, const int* in_sizes, int n_in,
                              void* d_out, int out_size, void* d_ws, size_t ws_size,
                              hipStream_t stream) {
    const float* x    = (const float*)d_in[0];
    const float* W_ih = (const float*)d_in[1];
    const float* W_hh = (const float*)d_in[2];
    const float* b_ih = (const float*)d_in[3];
    const float* b_hh = (const float*)d_in[4];
    const float* fc_W = (const float*)d_in[5];
    const float* fc_b = (const float*)d_in[6];
    float* out = (float*)d_out;

    rnn_fused_kernel<<<RNN_B, 512, 0, stream>>>(x, W_ih, W_hh, b_ih, b_hh, fc_W, fc_b, out);
}